// Round 7
// baseline (130.569 us; speedup 1.0000x reference)
//
#include <hip/hip_runtime.h>
#include <hip/hip_cooperative_groups.h>
#include <math.h>

namespace cg = cooperative_groups;

#define EPSF 1e-6f

__device__ __forceinline__ float fexp2(float x) {
    return __builtin_amdgcn_exp2f(x);   // v_exp_f32
}

// ============ shared phase logic (1024-thread blocks everywhere) ============

// Phase A: point i in [0,2n); writes pts[i] and 6-wide per-block partials.
// Called by 8 blocks x 1024 threads (2n = 8192 points).
__device__ __forceinline__ void phaseA_body(
        const float* __restrict__ src, const float* __restrict__ tgt, int n,
        int i, int tid, float4* __restrict__ pts, double* __restrict__ prepP,
        int pslot, double red[16][6]) {
    const float* p = (i < n) ? (src + 3 * i) : (tgt + 3 * (i - n));
    float x = p[0], y = p[1], z = p[2];
    float phi = 2.f * x + y + 1.f / (z + EPSF);
    float dphi = phi - 18.f;
    float w = expf(-(dphi * dphi) * (1.f / 128.f));
    pts[i] = make_float4(x, y, z, w);
    double acc[6];
    acc[0] = (double)(x * x + y * y + z * z);
    acc[1] = (double)x; acc[2] = (double)y; acc[3] = (double)z;
    acc[4] = (i < n) ? (double)w : 0.0;
    acc[5] = (i < n) ? 0.0 : (double)w;
    #pragma unroll
    for (int k = 0; k < 6; ++k) {
        double v = acc[k];
        for (int off = 32; off > 0; off >>= 1) v += __shfl_down(v, off);
        if ((tid & 63) == 0) red[tid >> 6][k] = v;
    }
    __syncthreads();
    if (tid < 6) {
        double s = 0.0;
        #pragma unroll
        for (int wv = 0; wv < 16; ++wv) s += red[wv][tid];
        prepP[pslot * 6 + tid] = s;
    }
}

// Bandwidth scalar from the 8 prep partial-slots (closed form, f64).
__device__ __forceinline__ float bw_scalar(const double* __restrict__ prepP, int n) {
    double S0 = 0, Sx = 0, Sy = 0, Sz = 0;
    for (int b = 0; b < 8; ++b) {
        S0 += prepP[b * 6 + 0];
        Sx += prepP[b * 6 + 1];
        Sy += prepP[b * 6 + 2];
        Sz += prepP[b * 6 + 3];
    }
    double ntf = 2.0 * (double)n;
    double sumL2 = 2.0 * ntf * S0 - 2.0 * (Sx * Sx + Sy * Sy + Sz * Sz);
    double bw = sumL2 / (ntf * ntf - ntf) * 0.25;   // / KERNEL_MUL^(5//2)
    return (float)(-1.4426950408889634 / bw);       // u = d*m; see exp chain below
}

// Phase B: block = 256-source x 256-target tile. 1024 threads: 4 threads per
// source point, each covering 64 of the 256 LDS-staged targets (the quarter
// index c = tid>>8 is wave-uniform -> LDS broadcast reads, conflict-free).
// exp chain: e = exp2(u/16); squarings give exp2(u/8), u/4, u/2, u.
// 1 trans + 4 muls instead of 5 trans per pair.
__device__ __forceinline__ double phaseB_body(
        const float4* __restrict__ pts, int n, float m,
        int bx, int by, int tid, float4* tg, double wsum[16]) {
    if (tid < 256) tg[tid] = pts[n + (by << 8) + tid];
    __syncthreads();
    int s = tid & 255;                  // source lane within tile (coalesced)
    int c = tid >> 8;                   // 0..3: target quarter (wave-uniform)
    float4 sp = pts[(bx << 8) + s];
    float a0 = 0.f;
    int j0 = c << 6;
    #pragma unroll 8
    for (int jj = 0; jj < 64; ++jj) {
        float4 t = tg[j0 + jj];
        float dx = sp.x - t.x, dy = sp.y - t.y, dz = sp.z - t.z;
        float d = dx * dx + dy * dy + dz * dz;
        float u = d * m;
        float e4 = fexp2(u * 0.0625f);  // exp2(u/16)
        float e3 = e4 * e4;             // exp2(u/8)
        float e2 = e3 * e3;             // exp2(u/4)
        float e1 = e2 * e2;             // exp2(u/2)
        float e0 = e1 * e1;             // exp2(u)
        a0 += t.w * (e0 + e1 + e2 + e3 + e4);
    }
    double v = (double)(a0 * sp.w);
    for (int off = 32; off > 0; off >>= 1) v += __shfl_down(v, off);
    if ((tid & 63) == 0) wsum[tid >> 6] = v;
    __syncthreads();
    double tot = 0.0;
    #pragma unroll
    for (int wv = 0; wv < 16; ++wv) tot += wsum[wv];
    return tot;
}

// Phase C: sum 256 tile partials + normalize (one block, 1024 threads).
__device__ __forceinline__ void phaseC_body(
        const double* __restrict__ prepP, const double* __restrict__ mainP,
        int tid, double wsum[16], float* __restrict__ out) {
    double a = (tid < 256) ? mainP[tid] : 0.0;
    for (int off = 32; off > 0; off >>= 1) a += __shfl_down(a, off);
    if ((tid & 63) == 0) wsum[tid >> 6] = a;
    __syncthreads();
    if (tid == 0) {
        double tot = 0.0;
        #pragma unroll
        for (int wv = 0; wv < 16; ++wv) tot += wsum[wv];
        double Sw = 0, Tw = 0;
        for (int b = 0; b < 8; ++b) {
            Sw += prepP[b * 6 + 4];
            Tw += prepP[b * 6 + 5];
        }
        out[0] = (float)(-2.0 * tot / ((Sw + (double)EPSF) * (Tw + (double)EPSF)));
    }
}

// ===== cooperative fused kernel: 256 blocks x 1024 thr (16 waves/CU, 50% occ) =====
__global__ __launch_bounds__(1024) void fused256(
    const float* __restrict__ src, const float* __restrict__ tgt, int n,
    float4* __restrict__ pts, double* __restrict__ prepP,
    double* __restrict__ mainP, float* __restrict__ out)
{
    cg::grid_group grid = cg::this_grid();
    const int tid = threadIdx.x;
    const int bid = blockIdx.x;

    __shared__ double red[16][6];
    __shared__ float4 tg[256];
    __shared__ double wsum[16];

    if (bid < 8)
        phaseA_body(src, tgt, n, bid * 1024 + tid, tid, pts, prepP, bid, red);

    grid.sync();

    float m = bw_scalar(prepP, n);
    double part = phaseB_body(pts, n, m, bid >> 4, bid & 15, tid, tg, wsum);
    if (tid == 0) mainP[bid] = part;

    grid.sync();

    if (bid == 0) {
        __syncthreads();                 // wsum reuse barrier
        phaseC_body(prepP, mainP, tid, wsum, out);
    }
}

// ============ fallback: 3 plain dispatches (no memset, no atomics) ============
__global__ __launch_bounds__(1024) void prep2(
    const float* __restrict__ src, const float* __restrict__ tgt, int n,
    float4* __restrict__ pts, double* __restrict__ prepP) {
    __shared__ double red[16][6];
    phaseA_body(src, tgt, n, blockIdx.x * 1024 + threadIdx.x, threadIdx.x,
                pts, prepP, blockIdx.x, red);
}

__global__ __launch_bounds__(1024) void main2(
    const float4* __restrict__ pts, int n,
    const double* __restrict__ prepP, double* __restrict__ mainP) {
    __shared__ float4 tg[256];
    __shared__ double wsum[16];
    float m = bw_scalar(prepP, n);
    double part = phaseB_body(pts, n, m, blockIdx.x, blockIdx.y,
                              threadIdx.x, tg, wsum);
    if (threadIdx.x == 0) mainP[blockIdx.y * 16 + blockIdx.x] = part;
}

__global__ __launch_bounds__(1024) void fin2(
    const double* __restrict__ prepP, const double* __restrict__ mainP,
    float* __restrict__ out) {
    __shared__ double wsum[16];
    phaseC_body(prepP, mainP, threadIdx.x, wsum, out);
}

extern "C" void kernel_launch(void* const* d_in, const int* in_sizes, int n_in,
                              void* d_out, int out_size, void* d_ws, size_t ws_size,
                              hipStream_t stream) {
    const float* src = (const float*)d_in[0];
    const float* tgt = (const float*)d_in[1];
    int n = in_sizes[0] / 3;            // 4096
    float* out = (float*)d_out;

    // ws layout: float4 pts[2n] | double prepP[8*6] | double mainP[256]
    char* ws = (char*)d_ws;
    float4* pts = (float4*)ws;
    size_t off = (size_t)(2 * n) * sizeof(float4);
    double* prepP = (double*)(ws + off);
    off += 8 * 6 * sizeof(double);
    double* mainP = (double*)(ws + off);

    void* args[] = {(void*)&src, (void*)&tgt, (void*)&n, (void*)&pts,
                    (void*)&prepP, (void*)&mainP, (void*)&out};
    hipError_t e = hipLaunchCooperativeKernel((void*)fused256, dim3(256),
                                              dim3(1024), args, 0, stream);
    if (e != hipSuccess) {
        (void)hipGetLastError();        // clear sticky error, take plain path
        prep2<<<8, 1024, 0, stream>>>(src, tgt, n, pts, prepP);
        main2<<<dim3(16, 16), 1024, 0, stream>>>(pts, n, prepP, mainP);
        fin2<<<1, 1024, 0, stream>>>(prepP, mainP, out);
    }
}

// Round 9
// 72.457 us; speedup vs baseline: 1.8020x; 1.8020x over previous
//
#include <hip/hip_runtime.h>
#include <math.h>

#define EPSF 1e-6f

__device__ __forceinline__ float fexp2(float x) {
    return __builtin_amdgcn_exp2f(x);   // v_exp_f32
}

// Confidence weight for one point.
__device__ __forceinline__ float conf_w(float x, float y, float z) {
    float phi = 2.f * x + y + 1.f / (z + EPSF);
    float dphi = phi - 18.f;
    return expf(-(dphi * dphi) * (1.f / 128.f));
}

// ============ main: redundant global sums + one 256x256 tile per block ============
// grid = 256 blocks x 1024 threads. No grid-wide sync anywhere:
// every block independently recomputes the 6 global sums (8192 points, L2-hot,
// ~1 us) so it derives the SAME bandwidth scalar m bit-exactly, then processes
// its own 256-source x 256-target tile (4 threads per source, wave-uniform
// target quarter -> LDS broadcast reads). Per-block f64 partial -> mainP[bid].
__global__ __launch_bounds__(1024) void mainK(
    const float* __restrict__ src, const float* __restrict__ tgt, int n,
    double* __restrict__ mainP, double* __restrict__ swtw)
{
    const int tid = threadIdx.x;
    const int bid = blockIdx.x;

    __shared__ double red[16][6];
    __shared__ double fsum[6];
    __shared__ float4 tg[256];
    __shared__ double wsum[16];

    // ---- redundant global sums over all 2n points ----
    double a0 = 0, a1 = 0, a2 = 0, a3 = 0, a4 = 0, a5 = 0;
    for (int i = tid; i < 2 * n; i += 1024) {
        const float* p = (i < n) ? (src + 3 * i) : (tgt + 3 * (i - n));
        float x = p[0], y = p[1], z = p[2];
        float w = conf_w(x, y, z);
        a0 += (double)(x * x + y * y + z * z);
        a1 += (double)x; a2 += (double)y; a3 += (double)z;
        if (i < n) a4 += (double)w; else a5 += (double)w;
    }
    double acc[6] = {a0, a1, a2, a3, a4, a5};
    #pragma unroll
    for (int k = 0; k < 6; ++k) {
        double v = acc[k];
        for (int off = 32; off > 0; off >>= 1) v += __shfl_down(v, off);
        if ((tid & 63) == 0) red[tid >> 6][k] = v;
    }
    __syncthreads();
    if (tid < 6) {                       // 16-way fold, one thread per sum
        double s = 0.0;
        #pragma unroll
        for (int wv = 0; wv < 16; ++wv) s += red[wv][tid];
        fsum[tid] = s;
    }
    __syncthreads();
    double S0 = fsum[0], Sx = fsum[1], Sy = fsum[2], Sz = fsum[3];

    double ntf = 2.0 * (double)n;
    double sumL2 = 2.0 * ntf * S0 - 2.0 * (Sx * Sx + Sy * Sy + Sz * Sz);
    double bw = sumL2 / (ntf * ntf - ntf) * 0.25;   // / KERNEL_MUL^(5//2)
    float m = (float)(-1.4426950408889634 / bw);    // u = d*m; exp chain below

    if (bid == 0 && tid == 0) { swtw[0] = fsum[4]; swtw[1] = fsum[5]; }

    // ---- stage this block's 256 targets (recompute w during staging) ----
    int bx = bid >> 4, by = bid & 15;
    if (tid < 256) {
        const float* p = tgt + 3 * ((by << 8) + tid);
        float x = p[0], y = p[1], z = p[2];
        tg[tid] = make_float4(x, y, z, conf_w(x, y, z));
    }
    __syncthreads();

    // ---- pairwise tile: 4 threads per source, 64 targets each ----
    int s = tid & 255;                  // source lane (coalesced)
    int c = tid >> 8;                   // 0..3: target quarter (wave-uniform)
    const float* p = src + 3 * ((bx << 8) + s);
    float sx = p[0], sy = p[1], sz = p[2];
    float sw = conf_w(sx, sy, sz);
    float acc0 = 0.f;
    int j0 = c << 6;
    #pragma unroll 8
    for (int jj = 0; jj < 64; ++jj) {
        float4 t = tg[j0 + jj];         // uniform idx -> LDS broadcast
        float dx = sx - t.x, dy = sy - t.y, dz = sz - t.z;
        float d = dx * dx + dy * dy + dz * dz;
        float u = d * m;
        float e4 = fexp2(u * 0.0625f);  // exp2(u/16)
        float e3 = e4 * e4;             // exp2(u/8)
        float e2 = e3 * e3;             // exp2(u/4)
        float e1 = e2 * e2;             // exp2(u/2)
        float e0 = e1 * e1;             // exp2(u)
        acc0 += t.w * (e0 + e1 + e2 + e3 + e4);
    }
    double v = (double)(acc0 * sw);
    for (int off = 32; off > 0; off >>= 1) v += __shfl_down(v, off);
    if ((tid & 63) == 0) wsum[tid >> 6] = v;
    __syncthreads();
    if (tid == 0) {
        double tot = 0.0;
        #pragma unroll
        for (int wv = 0; wv < 16; ++wv) tot += wsum[wv];
        mainP[bid] = tot;
    }
}

// ============ fin: sum 256 partials + normalize ============
__global__ __launch_bounds__(256) void finK(
    const double* __restrict__ mainP, const double* __restrict__ swtw,
    float* __restrict__ out)
{
    const int tid = threadIdx.x;
    __shared__ double wsum[4];
    double a = mainP[tid];
    for (int off = 32; off > 0; off >>= 1) a += __shfl_down(a, off);
    if ((tid & 63) == 0) wsum[tid >> 6] = a;
    __syncthreads();
    if (tid == 0) {
        double tot = wsum[0] + wsum[1] + wsum[2] + wsum[3];
        double denom = (swtw[0] + (double)EPSF) * (swtw[1] + (double)EPSF);
        out[0] = (float)(-2.0 * tot / denom);
    }
}

extern "C" void kernel_launch(void* const* d_in, const int* in_sizes, int n_in,
                              void* d_out, int out_size, void* d_ws, size_t ws_size,
                              hipStream_t stream) {
    const float* src = (const float*)d_in[0];
    const float* tgt = (const float*)d_in[1];
    int n = in_sizes[0] / 3;            // 4096
    float* out = (float*)d_out;

    // ws layout: double mainP[256] | double swtw[2]  (all written before read)
    double* mainP = (double*)d_ws;
    double* swtw = mainP + 256;

    mainK<<<256, 1024, 0, stream>>>(src, tgt, n, mainP, swtw);
    finK<<<1, 256, 0, stream>>>(mainP, swtw, out);
}